// Round 6
// baseline (378.938 us; speedup 1.0000x reference)
//
#include <hip/hip_runtime.h>
#include <hip/hip_bf16.h>

typedef __hip_bfloat16 bf16;
typedef __attribute__((ext_vector_type(8))) short short8;
typedef __attribute__((ext_vector_type(4))) float floatx4;
typedef __attribute__((ext_vector_type(4))) short shortx4;

static constexpr int BATCH = 4;
static constexpr int CH    = 512;   // C
static constexpr int SEQ   = 4096;  // H*W
static constexpr int DM    = 512;   // model dim

__device__ __forceinline__ void gload16(const void* g, void* l) {
  __builtin_amdgcn_global_load_lds(
      (const __attribute__((address_space(1))) unsigned int*)g,
      (__attribute__((address_space(3))) unsigned int*)l,
      16, 0, 0);
}

// ---------------------------------------------------------------------------
// Weight fp32 -> bf16 conversion (4 matrices of 512x512)
// ---------------------------------------------------------------------------
__global__ __launch_bounds__(256) void cvt_weights(
    const float* __restrict__ w0, const float* __restrict__ w1,
    const float* __restrict__ w2, const float* __restrict__ w3,
    bf16* __restrict__ out) {
  const float* src = (blockIdx.y == 0) ? w0 : (blockIdx.y == 1) ? w1
                   : (blockIdx.y == 2) ? w2 : w3;
  int idx = blockIdx.x * 256 + threadIdx.x;
  out[(long)blockIdx.y * (DM * CH) + idx] = __float2bfloat16(src[idx]);
}

// ---------------------------------------------------------------------------
// x (b,c,s) fp32 -> xT (b,s,c) bf16, 64x64 LDS tiles
// ---------------------------------------------------------------------------
__global__ __launch_bounds__(256) void transpose_cvt(
    const float* __restrict__ x, bf16* __restrict__ xT) {
  __shared__ float tile[64][65];
  const int s0 = blockIdx.x * 64, c0 = blockIdx.y * 64;
  const float* xb = x + (long)blockIdx.z * CH * SEQ;
  bf16* xTb = xT + (long)blockIdx.z * SEQ * CH;
  const int t = threadIdx.x;
  const int sl = t & 63, cq = t >> 6;
  #pragma unroll
  for (int i = 0; i < 16; ++i) {
    int cl = cq * 16 + i;
    tile[cl][sl] = xb[(long)(c0 + cl) * SEQ + s0 + sl];
  }
  __syncthreads();
  const int cl2 = t & 63, sq = t >> 6;
  #pragma unroll
  for (int i = 0; i < 16; ++i) {
    int sl2 = sq * 16 + i;
    xTb[(long)(s0 + sl2) * CH + c0 + cl2] = __float2bfloat16(tile[cl2][sl2]);
  }
}

// ---------------------------------------------------------------------------
// gemm_qk: 256x256 tile QK^T (round-5 structure, kept as-is).
// ---------------------------------------------------------------------------
__global__ __launch_bounds__(512, 2) void gemm_qk(
    const bf16* __restrict__ A, long sAz,
    const bf16* __restrict__ B, long sBz,
    bf16* __restrict__ C, long sCz,
    float scale, int K, int ldc) {
  __shared__ __align__(16) bf16 As[2][256 * 64];
  __shared__ __align__(16) bf16 Bs[2][256 * 64];

  int id = blockIdx.x + gridDim.x * (blockIdx.y + gridDim.y * blockIdx.z);
  int nwg = gridDim.x * gridDim.y * gridDim.z;
  int sid = ((nwg & 7) == 0) ? ((id & 7) * (nwg >> 3) + (id >> 3)) : id;
  const int bx = sid % gridDim.x;
  const int by = (sid / gridDim.x) % gridDim.y;
  const int bz = sid / (gridDim.x * gridDim.y);

  const int tid = threadIdx.x;
  const long lK = K;
  const bf16* Ab = A + (long)bz * sAz + (long)by * 256 * lK;
  const bf16* Bb = B + (long)bz * sBz + (long)bx * 256 * lK;

  const int w = tid >> 6, lane = tid & 63;
  const int wr = w >> 2, wc = w & 3;          // 2 x 4 wave grid
  const int l16 = lane & 15, quad = lane >> 4;

  const int srow = tid >> 3;                  // 0..63
  const int sp = tid & 7;                     // physical 16B slot
  const int slog = (sp ^ (srow & 7)) << 3;    // pre-swizzled source column

  const int pA0 = (quad ^ (l16 & 7)) << 3;
  const int pA1 = pA0 ^ 32;

  auto stage_half = [&](const bf16* Gb, bf16* Lb, int kt, int h) {
    #pragma unroll
    for (int r = 0; r < 2; ++r) {
      const int row = h * 128 + r * 64 + srow;
      gload16(Gb + (long)kt * 64 + (long)row * lK + slog,
              (char*)Lb + row * 128 + sp * 16);
    }
  };

  floatx4 acc[8][4];
  #pragma unroll
  for (int m = 0; m < 8; ++m)
    #pragma unroll
    for (int n = 0; n < 4; ++n) acc[m][n] = (floatx4)(0.0f);

  const int nk = K >> 6;  // even
  stage_half(Ab, &As[0][0], 0, 0); stage_half(Bb, &Bs[0][0], 0, 0);
  stage_half(Ab, &As[0][0], 0, 1); stage_half(Bb, &Bs[0][0], 0, 1);
  if (nk > 1) { stage_half(Ab, &As[1][0], 1, 0); stage_half(Bb, &Bs[1][0], 1, 0); }
  asm volatile("s_waitcnt vmcnt(4)" ::: "memory");
  __builtin_amdgcn_s_barrier();

  for (int tt = 0; tt < nk; tt += 2) {
    #pragma unroll
    for (int u = 0; u < 2; ++u) {
      const bf16* __restrict__ Al = &As[u][0];
      const bf16* __restrict__ Bl = &Bs[u][0];
      short8 a[2][4], b[2][2][2];
      #pragma unroll
      for (int p = 0; p < 4; ++p) {
        const int rm = p >> 1, cn = p & 1;
        if (cn == 0) {
          #pragma unroll
          for (int kc = 0; kc < 2; ++kc)
            #pragma unroll
            for (int i = 0; i < 4; ++i)
              a[kc][i] = *(const short8*)(
                  Al + (rm * 128 + wr * 64 + i * 16 + l16) * 64
                     + (kc ? pA1 : pA0));
        }
        if (rm == 0) {
          #pragma unroll
          for (int kc = 0; kc < 2; ++kc)
            #pragma unroll
            for (int j = 0; j < 2; ++j)
              b[kc][cn][j] = *(const short8*)(
                  Bl + (cn * 128 + wc * 32 + j * 16 + l16) * 64
                     + (kc ? pA1 : pA0));
        }
        {
          const int g = u * 4 + p;
          const int stile = tt + 1 + ((g + 2) >> 2);
          if (stile < nk) {
            const int sh = (p < 2) ? 1 : 0;
            if (p & 1) stage_half(Bb, &Bs[stile & 1][0], stile, sh);
            else       stage_half(Ab, &As[stile & 1][0], stile, sh);
          }
        }
        __builtin_amdgcn_sched_barrier(0);
        __builtin_amdgcn_s_barrier();
        asm volatile("s_waitcnt lgkmcnt(0)" ::: "memory");
        __builtin_amdgcn_sched_barrier(0);
        __builtin_amdgcn_s_setprio(1);
        #pragma unroll
        for (int kc = 0; kc < 2; ++kc)
          #pragma unroll
          for (int i = 0; i < 4; ++i)
            #pragma unroll
            for (int j = 0; j < 2; ++j)
              acc[rm * 4 + i][cn * 2 + j] =
                  __builtin_amdgcn_mfma_f32_16x16x32_bf16(
                      a[kc][i], b[kc][cn][j], acc[rm * 4 + i][cn * 2 + j],
                      0, 0, 0);
        __builtin_amdgcn_s_setprio(0);
        if (p == 3) {
          if (u == 0) {
            if (tt + 2 < nk) asm volatile("s_waitcnt vmcnt(4)" ::: "memory");
            else             asm volatile("s_waitcnt vmcnt(0)" ::: "memory");
          } else {
            if (tt + 2 < nk) asm volatile("s_waitcnt vmcnt(4)" ::: "memory");
          }
        }
        __builtin_amdgcn_s_barrier();
      }
    }
  }

  bf16* Cb = C + (long)bz * sCz;
  #pragma unroll
  for (int rm = 0; rm < 2; ++rm)
    #pragma unroll
    for (int i = 0; i < 4; ++i) {
      const int row = by * 256 + rm * 128 + wr * 64 + i * 16 + quad * 4;
      #pragma unroll
      for (int cn = 0; cn < 2; ++cn)
        #pragma unroll
        for (int j = 0; j < 2; ++j) {
          const int col = bx * 256 + cn * 128 + wc * 32 + j * 16 + l16;
          floatx4 v = acc[rm * 4 + i][cn * 2 + j];
          #pragma unroll
          for (int r = 0; r < 4; ++r)
            Cb[(long)(row + r) * ldc + col] = __float2bfloat16(v[r] * scale);
        }
    }
}

// ---------------------------------------------------------------------------
// fused_smpv: softmax + PV in one kernel. BM=64 q-rows (exclusively owned),
// BN=512 (full D), K=4096 kv. Grid 64x4 = 256 blocks = 1/CU.
// Pass 1: online per-row max m and exp-sum l over the block's 64 Sim rows
//   (8 threads/row, shfl_xor combine). 1/l kept in LDS for the epilogue.
// Pass 2: BT-GEMM O = P * Vt^T in 64-wide kv chunks. A-tile (P) is
//   REG-staged: load Sim chunk -> exp(x - m) -> bf16 -> swizzled ds_write
//   (T14 async-split: load issued before MFMA, write after). B (Vt chunk,
//   512x64) staged via gload16 with pre-swizzled source (T2). 8 waves each
//   own 64 d-cols (1Mx8N); per wave 64x64 out = acc[4][4]. One barrier per
//   chunk (staging targets nxt buffer only -> no mid-chunk barrier needed).
// Block-id remap: consecutive hw ids round-robin XCDs; decode gives each
//   XCD a single batch so Vt (4MB/batch) stays L2-resident.
// ---------------------------------------------------------------------------
__global__ __launch_bounds__(512, 2) void fused_smpv(
    const bf16* __restrict__ Sim, const bf16* __restrict__ Vt,
    bf16* __restrict__ Ob) {
  __shared__ __align__(16) bf16 Apv[2][64 * 64];    // P chunk (8KB each)
  __shared__ __align__(16) bf16 Bpv[2][512 * 64];   // Vt chunk (64KB each)
  __shared__ float rl_lds[64];

  const int id = blockIdx.x + (blockIdx.y << 6);    // 0..255
  const int bz = (id >> 1) & 3;                     // batch
  const int by = ((id >> 3) << 1) | (id & 1);       // q row-tile 0..63

  const int tid = threadIdx.x;
  const bf16* Simb = Sim + (long)bz * ((long)SEQ * SEQ) + (long)(by * 64) * SEQ;
  const bf16* Vb   = Vt  + (long)bz * ((long)SEQ * CH);
  bf16* Obb        = Ob  + (long)bz * ((long)SEQ * CH) + (long)(by * 64) * CH;

  const int srow = tid >> 3;        // 0..63: A row / pass-1 row / stage row
  const int sp = tid & 7;           // 16B slot
  const int slog = (sp ^ (srow & 7)) << 3;   // pre-swizzled source col (elems)
  const int aswz = (sp ^ (srow & 7)) << 4;   // swizzled LDS byte slot

  // ---- pass 1: online row max + exp-sum ----
  float m = -3.0e38f, l = 0.f;
  {
    const uint4* pr = (const uint4*)(Simb + (long)srow * SEQ) + sp;
    for (int c = 0; c < 64; ++c) {
      uint4 u = pr[c * 8];
      const ushort* h = (const ushort*)&u;
      float v[8];
      float vm = -3.0e38f;
      #pragma unroll
      for (int k2 = 0; k2 < 8; ++k2) {
        v[k2] = __uint_as_float(((unsigned)h[k2]) << 16);
        vm = fmaxf(vm, v[k2]);
      }
      if (vm > m) { l *= __expf(m - vm); m = vm; }
      #pragma unroll
      for (int k2 = 0; k2 < 8; ++k2) l += __expf(v[k2] - m);
    }
    #pragma unroll
    for (int o = 1; o < 8; o <<= 1) {
      float m2 = __shfl_xor(m, o), l2 = __shfl_xor(l, o);
      float nm = fmaxf(m, m2);
      l = l * __expf(m - nm) + l2 * __expf(m2 - nm);
      m = nm;
    }
    if (sp == 0) rl_lds[srow] = 1.0f / l;
  }

  const int w = tid >> 6, lane = tid & 63;
  const int l16 = lane & 15, quad = lane >> 4;
  const int pA0 = (quad ^ (l16 & 7)) << 3;
  const int pA1 = pA0 ^ 32;

  auto stageB8 = [&](int buf, int kt) {
    const bf16* s = Vb + (long)srow * SEQ + kt * 64 + slog;
    char* d = (char*)(&Bpv[buf][0]) + tid * 16;
    #pragma unroll
    for (int r = 0; r < 8; ++r)
      gload16(s + (long)(r * 64) * SEQ, d + r * 8192);
  };
  auto writeA = [&](int buf, uint4 u) {
    const ushort* h = (const ushort*)&u;
    union { uint4 u4; ushort hh[8]; } pk;
    #pragma unroll
    for (int k2 = 0; k2 < 8; ++k2) {
      float f = __uint_as_float(((unsigned)h[k2]) << 16);
      __hip_bfloat16 pb = __float2bfloat16(__expf(f - m));
      pk.hh[k2] = *(const ushort*)&pb;
    }
    *(uint4*)((char*)(&Apv[buf][0]) + srow * 128 + aswz) = pk.u4;
  };

  // ---- prologue: chunk 0 ----
  {
    uint4 ua = *(const uint4*)(Simb + (long)srow * SEQ + sp * 8);
    stageB8(0, 0);
    writeA(0, ua);
  }
  __syncthreads();

  floatx4 acc[4][4];
  #pragma unroll
  for (int i = 0; i < 4; ++i)
    #pragma unroll
    for (int j = 0; j < 4; ++j) acc[i][j] = (floatx4)(0.0f);

  const int nk = SEQ >> 6;  // 64 chunks
  for (int t = 0; t < nk; ++t) {
    const int cur = t & 1, nxt = cur ^ 1;
    const bool more = (t + 1 < nk);
    uint4 un;
    if (more) {
      un = *(const uint4*)(Simb + (long)srow * SEQ + (t + 1) * 64 + sp * 8);
      stageB8(nxt, t + 1);
    }
    short8 a[2][4], b[2][4];
    #pragma unroll
    for (int kc = 0; kc < 2; ++kc) {
      const int poff = kc ? pA1 : pA0;
      #pragma unroll
      for (int i = 0; i < 4; ++i)
        a[kc][i] = *(const short8*)(&Apv[cur][0] + (i * 16 + l16) * 64 + poff);
      #pragma unroll
      for (int j = 0; j < 4; ++j)
        b[kc][j] = *(const short8*)(&Bpv[cur][0]
                                    + (w * 64 + j * 16 + l16) * 64 + poff);
    }
    __builtin_amdgcn_s_setprio(1);
    #pragma unroll
    for (int kc = 0; kc < 2; ++kc)
      #pragma unroll
      for (int i = 0; i < 4; ++i)
        #pragma unroll
        for (int j = 0; j < 4; ++j)
          acc[i][j] = __builtin_amdgcn_mfma_f32_16x16x32_bf16(
              a[kc][i], b[kc][j], acc[i][j], 0, 0, 0);
    __builtin_amdgcn_s_setprio(0);
    if (more) writeA(nxt, un);
    __syncthreads();  // drains B gloads (vmcnt 0) + A ds_write, swap-safe
  }

  // ---- epilogue: O * (1/l), bf16, row-major [s][d] ----
  #pragma unroll
  for (int i = 0; i < 4; ++i) {
    #pragma unroll
    for (int j = 0; j < 4; ++j) {
      floatx4 v = acc[i][j];
      const int col = w * 64 + j * 16 + l16;
      #pragma unroll
      for (int r = 0; r < 4; ++r) {
        const int row = i * 16 + quad * 4 + r;
        Obb[(long)row * CH + col] = __float2bfloat16(v[r] * rl_lds[row]);
      }
    }
  }
}

// ---------------------------------------------------------------------------
// gemm_bn128: 256x128 tile, BK=64, 8 waves in 4Mx2N grid, per-wave 64x64.
// 2 phases per K-tile; TRIPLE-buffered LDS + counted vmcnt(6) (t+2 staging).
// MODE 0: bf16 = acc + bias[col], C[row*ldc+col]
// MODE 1: bf16 = acc + bias[col], transposed C[col*ldc+row]
// MODE 4: f32  = acc + bias[col], transposed C[col*ldc+row]
// ---------------------------------------------------------------------------
template <int MODE>
__global__ __launch_bounds__(512, 2) void gemm_bn128(
    const bf16* __restrict__ A, long sAz,
    const bf16* __restrict__ B, long sBz,
    void* __restrict__ Cv, long sCz,
    const float* __restrict__ bias, float scale,
    int K, int ldc) {
  __shared__ __align__(16) bf16 As[3][256 * 64];
  __shared__ __align__(16) bf16 Bs[3][128 * 64];

  int id = blockIdx.x + gridDim.x * (blockIdx.y + gridDim.y * blockIdx.z);
  int nwg = gridDim.x * gridDim.y * gridDim.z;
  int sid = ((nwg & 7) == 0) ? ((id & 7) * (nwg >> 3) + (id >> 3)) : id;
  const int bx = sid % gridDim.x;
  const int by = (sid / gridDim.x) % gridDim.y;
  const int bz = sid / (gridDim.x * gridDim.y);

  const int tid = threadIdx.x;
  const long lK = K;
  const bf16* Ab = A + (long)bz * sAz + (long)by * 256 * lK;
  const bf16* Bb = B + (long)bz * sBz + (long)bx * 128 * lK;

  const int w = tid >> 6, lane = tid & 63;
  const int wr = w >> 1, wc = w & 1;          // 4 x 2 wave grid
  const int l16 = lane & 15, quad = lane >> 4;

  const int srow = tid >> 3;
  const int sp = tid & 7;
  const int slog = (sp ^ (srow & 7)) << 3;

  const int pA0 = (quad ^ (l16 & 7)) << 3;
  const int pA1 = pA0 ^ 32;

  auto stageA = [&](int buf, int kt) {
    const bf16* s = Ab + (long)kt * 64 + (long)srow * lK + slog;
    char* d = (char*)(&As[buf][0]) + tid * 16;
    #pragma unroll
    for (int r = 0; r < 4; ++r)
      gload16(s + (long)(r * 64) * lK, d + r * 8192);
  };
  auto stageB = [&](int buf, int kt) {
    const bf16* s = Bb + (long)kt * 64 + (long)srow * lK + slog;
    char* d = (char*)(&Bs[buf][0]) + tid * 16;
    #pragma unroll
    for (int r = 0; r < 2; ++r)
      gload16(s + (long)(r * 64) * lK, d + r * 8192);
  };

  floatx4 acc[4][4];
  #pragma unroll
  for (int m = 0; m < 4; ++m)
    #pragma unroll
    for (int n = 0; n < 4; ++n) acc[m][n] = (floatx4)(0.0f);

  const int nk = K >> 6;
  stageA(0, 0); stageB(0, 0);
  stageA(1, 1); stageB(1, 1);
  asm volatile("s_waitcnt vmcnt(6)" ::: "memory");
  __builtin_amdgcn_s_barrier();

  int bcur = 0, bstage = 2;
  for (int t = 0; t < nk; ++t) {
    const bf16* __restrict__ Al = &As[bcur][0];
    const bf16* __restrict__ Bl = &Bs[bcur][0];
    const bool more = (t + 2 < nk);
    #pragma unroll
    for (int kc = 0; kc < 2; ++kc) {
      const int poff = kc ? pA1 : pA0;
      short8 a[4], b[4];
      #pragma unroll
      for (int i = 0; i < 4; ++i)
        a[i] = *(const short8*)(Al + (wr * 64 + i * 16 + l16) * 64 + poff);
      #pragma unroll
      for (int j = 0; j < 4; ++j)
        b[j] = *(const short8*)(Bl + (wc * 64 + j * 16 + l16) * 64 + poff);
      if (more) {
        if (kc == 0) stageA(bstage, t + 2);
        else         stageB(bstage, t + 2);
      }
      __builtin_amdgcn_s_barrier();
      __builtin_amdgcn_s_setprio(1);
      #pragma unroll
      for (int i = 0; i < 4; ++i)
        #pragma unroll
        for (int j = 0; j < 4; ++j)
          acc[i][j] = __builtin_amdgcn_mfma_f32_16x16x32_bf16(
              a[i], b[j], acc[i][j], 0, 0, 0);
      __builtin_amdgcn_s_setprio(0);
      if (kc == 1) {
        if (more)            asm volatile("s_waitcnt vmcnt(6)" ::: "memory");
        else if (t + 1 < nk) asm volatile("s_waitcnt vmcnt(0)" ::: "memory");
      }
      __builtin_amdgcn_s_barrier();
    }
    bcur = (bcur == 2) ? 0 : bcur + 1;
    bstage = (bstage == 2) ? 0 : bstage + 1;
  }

  const int rbase = by * 256 + wr * 64 + quad * 4;
  const int cbase = bx * 128 + wc * 64 + l16;
  #pragma unroll
  for (int m = 0; m < 4; ++m) {
    const int row = rbase + m * 16;
    #pragma unroll
    for (int n = 0; n < 4; ++n) {
      const int col = cbase + n * 16;
      floatx4 v = acc[m][n];
      if constexpr (MODE == 0) {
        bf16* C = (bf16*)Cv + (long)bz * sCz;
        const float bb = bias[col];
        #pragma unroll
        for (int r = 0; r < 4; ++r)
          C[(long)(row + r) * ldc + col] = __float2bfloat16(v[r] + bb);
      } else if constexpr (MODE == 1) {
        bf16* C = (bf16*)Cv + (long)bz * sCz;
        const float bb = bias[col];
        alignas(8) bf16 tmp[4];
        #pragma unroll
        for (int r = 0; r < 4; ++r) tmp[r] = __float2bfloat16(v[r] + bb);
        *(shortx4*)(C + (long)col * ldc + row) = *(const shortx4*)tmp;
      } else {  // MODE 4
        float* C = (float*)Cv + (long)bz * sCz;
        const float bb = bias[col];
        floatx4 o_;
        #pragma unroll
        for (int r = 0; r < 4; ++r) o_[r] = v[r] + bb;
        *(floatx4*)(C + (long)col * ldc + row) = o_;
      }
    }
  }
}

// ---------------------------------------------------------------------------
extern "C" void kernel_launch(void* const* d_in, const int* in_sizes, int n_in,
                              void* d_out, int out_size, void* d_ws,
                              size_t ws_size, hipStream_t stream) {
  const float* q  = (const float*)d_in[0];
  const float* Wq = (const float*)d_in[1];
  const float* bq = (const float*)d_in[2];
  const float* Wk = (const float*)d_in[3];
  const float* bk = (const float*)d_in[4];
  const float* Wv = (const float*)d_in[5];
  const float* bv = (const float*)d_in[6];
  const float* Wo = (const float*)d_in[7];
  const float* bo = (const float*)d_in[8];
  float* out = (float*)d_out;

  bf16* ws = (bf16*)d_ws;
  const long WSZ = (long)DM * CH;         // 262144 elems per weight matrix
  const long XSZ = (long)SEQ * CH;        // 2097152 elems per batch
  const long SSZ = (long)SEQ * SEQ;       // 16777216 elems per batch
  bf16* Wqb = ws;
  bf16* Wkb = Wqb + WSZ;
  bf16* Wvb = Wqb + 2 * WSZ;
  bf16* Wob = Wqb + 3 * WSZ;
  bf16* xT  = Wqb + 4 * WSZ;
  bf16* Qb  = xT + BATCH * XSZ;
  bf16* Kb  = Qb + BATCH * XSZ;
  bf16* Vt  = Kb + BATCH * XSZ;   // (b, d, s) layout
  bf16* Ob  = Vt + BATCH * XSZ;
  bf16* Sim = Ob + BATCH * XSZ;   // (b, s, t) bf16

  cvt_weights<<<dim3(WSZ / 256, 4), 256, 0, stream>>>(Wq, Wk, Wv, Wo, ws);
  transpose_cvt<<<dim3(SEQ / 64, CH / 64, BATCH), 256, 0, stream>>>(q, xT);

  // Q = xT * Wq^T + bq  (4096x512x512), bf16 out, row-major [s][d]
  gemm_bn128<0><<<dim3(4, 16, BATCH), 512, 0, stream>>>(
      xT, XSZ, Wqb, 0, Qb, XSZ, bq, 1.f, CH, DM);
  gemm_bn128<0><<<dim3(4, 16, BATCH), 512, 0, stream>>>(
      xT, XSZ, Wkb, 0, Kb, XSZ, bk, 1.f, CH, DM);
  // V stored transposed: Vt[d][s]
  gemm_bn128<1><<<dim3(4, 16, BATCH), 512, 0, stream>>>(
      xT, XSZ, Wvb, 0, Vt, XSZ, bv, 1.f, CH, SEQ);
  // sim = Q*K^T * scale (4096x4096x512)
  gemm_qk<<<dim3(16, 16, BATCH), 512, 0, stream>>>(
      Qb, XSZ, Kb, XSZ, Sim, SSZ, 0.04419417382415922f, CH, SEQ);
  // o = softmax(sim) * V, fused (no softmax round-trip)
  fused_smpv<<<dim3(64, 4), 512, 0, stream>>>(Sim, Vt, Ob);
  // y = o * Wo^T + bo, stored transposed into d_out as (b, c, s) fp32
  gemm_bn128<4><<<dim3(4, 16, BATCH), 512, 0, stream>>>(
      Ob, XSZ, Wob, 0, out, XSZ, bo, 1.f, DM, SEQ);
}

// Round 9
// 352.556 us; speedup vs baseline: 1.0748x; 1.0748x over previous
//
#include <hip/hip_runtime.h>
#include <hip/hip_bf16.h>

typedef __hip_bfloat16 bf16;
typedef __attribute__((ext_vector_type(8))) short short8;
typedef __attribute__((ext_vector_type(4))) float floatx4;
typedef __attribute__((ext_vector_type(4))) short shortx4;

static constexpr int BATCH = 4;
static constexpr int CH    = 512;   // C
static constexpr int SEQ   = 4096;  // H*W
static constexpr int DM    = 512;   // model dim

__device__ __forceinline__ void gload16(const void* g, void* l) {
  __builtin_amdgcn_global_load_lds(
      (const __attribute__((address_space(1))) unsigned int*)g,
      (__attribute__((address_space(3))) unsigned int*)l,
      16, 0, 0);
}

// 2^x via the hardware transcendental (avoids glibc __exp2f macro collision)
__device__ __forceinline__ float hw_exp2(float x) {
  float r;
  asm("v_exp_f32 %0, %1" : "=v"(r) : "v"(x));
  return r;
}

// ---------------------------------------------------------------------------
// Weight fp32 -> bf16 conversion (4 matrices of 512x512)
// ---------------------------------------------------------------------------
__global__ __launch_bounds__(256) void cvt_weights(
    const float* __restrict__ w0, const float* __restrict__ w1,
    const float* __restrict__ w2, const float* __restrict__ w3,
    bf16* __restrict__ out) {
  const float* src = (blockIdx.y == 0) ? w0 : (blockIdx.y == 1) ? w1
                   : (blockIdx.y == 2) ? w2 : w3;
  int idx = blockIdx.x * 256 + threadIdx.x;
  out[(long)blockIdx.y * (DM * CH) + idx] = __float2bfloat16(src[idx]);
}

// ---------------------------------------------------------------------------
// x (b,c,s) fp32 -> xT (b,s,c) bf16, 64x64 LDS tiles
// ---------------------------------------------------------------------------
__global__ __launch_bounds__(256) void transpose_cvt(
    const float* __restrict__ x, bf16* __restrict__ xT) {
  __shared__ float tile[64][65];
  const int s0 = blockIdx.x * 64, c0 = blockIdx.y * 64;
  const float* xb = x + (long)blockIdx.z * CH * SEQ;
  bf16* xTb = xT + (long)blockIdx.z * SEQ * CH;
  const int t = threadIdx.x;
  const int sl = t & 63, cq = t >> 6;
  #pragma unroll
  for (int i = 0; i < 16; ++i) {
    int cl = cq * 16 + i;
    tile[cl][sl] = xb[(long)(c0 + cl) * SEQ + s0 + sl];
  }
  __syncthreads();
  const int cl2 = t & 63, sq = t >> 6;
  #pragma unroll
  for (int i = 0; i < 16; ++i) {
    int sl2 = sq * 16 + i;
    xTb[(long)(s0 + sl2) * CH + c0 + cl2] = __float2bfloat16(tile[cl2][sl2]);
  }
}

// ---------------------------------------------------------------------------
// gemm_qk: 256x256 tile QK^T. Output is PRE-SCALED by scale*log2(e) so the
// downstream softmax can use exp2 directly (softmax is invariant to the
// subtract; the log2e factor converts e^x to 2^x).
// ---------------------------------------------------------------------------
__global__ __launch_bounds__(512, 2) void gemm_qk(
    const bf16* __restrict__ A, long sAz,
    const bf16* __restrict__ B, long sBz,
    bf16* __restrict__ C, long sCz,
    float scale, int K, int ldc) {
  __shared__ __align__(16) bf16 As[2][256 * 64];
  __shared__ __align__(16) bf16 Bs[2][256 * 64];

  int id = blockIdx.x + gridDim.x * (blockIdx.y + gridDim.y * blockIdx.z);
  int nwg = gridDim.x * gridDim.y * gridDim.z;
  int sid = ((nwg & 7) == 0) ? ((id & 7) * (nwg >> 3) + (id >> 3)) : id;
  const int bx = sid % gridDim.x;
  const int by = (sid / gridDim.x) % gridDim.y;
  const int bz = sid / (gridDim.x * gridDim.y);

  const int tid = threadIdx.x;
  const long lK = K;
  const bf16* Ab = A + (long)bz * sAz + (long)by * 256 * lK;
  const bf16* Bb = B + (long)bz * sBz + (long)bx * 256 * lK;

  const int w = tid >> 6, lane = tid & 63;
  const int wr = w >> 2, wc = w & 3;          // 2 x 4 wave grid
  const int l16 = lane & 15, quad = lane >> 4;

  const int srow = tid >> 3;                  // 0..63
  const int sp = tid & 7;                     // physical 16B slot
  const int slog = (sp ^ (srow & 7)) << 3;    // pre-swizzled source column

  const int pA0 = (quad ^ (l16 & 7)) << 3;
  const int pA1 = pA0 ^ 32;

  auto stage_half = [&](const bf16* Gb, bf16* Lb, int kt, int h) {
    #pragma unroll
    for (int r = 0; r < 2; ++r) {
      const int row = h * 128 + r * 64 + srow;
      gload16(Gb + (long)kt * 64 + (long)row * lK + slog,
              (char*)Lb + row * 128 + sp * 16);
    }
  };

  floatx4 acc[8][4];
  #pragma unroll
  for (int m = 0; m < 8; ++m)
    #pragma unroll
    for (int n = 0; n < 4; ++n) acc[m][n] = (floatx4)(0.0f);

  const int nk = K >> 6;  // even
  stage_half(Ab, &As[0][0], 0, 0); stage_half(Bb, &Bs[0][0], 0, 0);
  stage_half(Ab, &As[0][0], 0, 1); stage_half(Bb, &Bs[0][0], 0, 1);
  if (nk > 1) { stage_half(Ab, &As[1][0], 1, 0); stage_half(Bb, &Bs[1][0], 1, 0); }
  asm volatile("s_waitcnt vmcnt(4)" ::: "memory");
  __builtin_amdgcn_s_barrier();

  for (int tt = 0; tt < nk; tt += 2) {
    #pragma unroll
    for (int u = 0; u < 2; ++u) {
      const bf16* __restrict__ Al = &As[u][0];
      const bf16* __restrict__ Bl = &Bs[u][0];
      short8 a[2][4], b[2][2][2];
      #pragma unroll
      for (int p = 0; p < 4; ++p) {
        const int rm = p >> 1, cn = p & 1;
        if (cn == 0) {
          #pragma unroll
          for (int kc = 0; kc < 2; ++kc)
            #pragma unroll
            for (int i = 0; i < 4; ++i)
              a[kc][i] = *(const short8*)(
                  Al + (rm * 128 + wr * 64 + i * 16 + l16) * 64
                     + (kc ? pA1 : pA0));
        }
        if (rm == 0) {
          #pragma unroll
          for (int kc = 0; kc < 2; ++kc)
            #pragma unroll
            for (int j = 0; j < 2; ++j)
              b[kc][cn][j] = *(const short8*)(
                  Bl + (cn * 128 + wc * 32 + j * 16 + l16) * 64
                     + (kc ? pA1 : pA0));
        }
        {
          const int g = u * 4 + p;
          const int stile = tt + 1 + ((g + 2) >> 2);
          if (stile < nk) {
            const int sh = (p < 2) ? 1 : 0;
            if (p & 1) stage_half(Bb, &Bs[stile & 1][0], stile, sh);
            else       stage_half(Ab, &As[stile & 1][0], stile, sh);
          }
        }
        __builtin_amdgcn_sched_barrier(0);
        __builtin_amdgcn_s_barrier();
        asm volatile("s_waitcnt lgkmcnt(0)" ::: "memory");
        __builtin_amdgcn_sched_barrier(0);
        __builtin_amdgcn_s_setprio(1);
        #pragma unroll
        for (int kc = 0; kc < 2; ++kc)
          #pragma unroll
          for (int i = 0; i < 4; ++i)
            #pragma unroll
            for (int j = 0; j < 2; ++j)
              acc[rm * 4 + i][cn * 2 + j] =
                  __builtin_amdgcn_mfma_f32_16x16x32_bf16(
                      a[kc][i], b[kc][cn][j], acc[rm * 4 + i][cn * 2 + j],
                      0, 0, 0);
        __builtin_amdgcn_s_setprio(0);
        if (p == 3) {
          if (u == 0) {
            if (tt + 2 < nk) asm volatile("s_waitcnt vmcnt(4)" ::: "memory");
            else             asm volatile("s_waitcnt vmcnt(0)" ::: "memory");
          } else {
            if (tt + 2 < nk) asm volatile("s_waitcnt vmcnt(4)" ::: "memory");
          }
        }
        __builtin_amdgcn_s_barrier();
      }
    }
  }

  bf16* Cb = C + (long)bz * sCz;
  #pragma unroll
  for (int rm = 0; rm < 2; ++rm)
    #pragma unroll
    for (int i = 0; i < 4; ++i) {
      const int row = by * 256 + rm * 128 + wr * 64 + i * 16 + quad * 4;
      #pragma unroll
      for (int cn = 0; cn < 2; ++cn)
        #pragma unroll
        for (int j = 0; j < 2; ++j) {
          const int col = bx * 256 + cn * 128 + wc * 32 + j * 16 + l16;
          floatx4 v = acc[rm * 4 + i][cn * 2 + j];
          #pragma unroll
          for (int r = 0; r < 4; ++r)
            Cb[(long)(row + r) * ldc + col] = __float2bfloat16(v[r] * scale);
        }
    }
}

// ---------------------------------------------------------------------------
// fused_smpv v2: SINGLE-PASS softmax + PV. Sim holds scores pre-scaled by
// scale*log2e; P = 2^sim (no max subtraction -- scores are O(+-1), exp is
// fp32-safe; softmax is shift-invariant so result matches reference).
// l (= sum of 2^sim per row) is accumulated during P staging and applied in
// the epilogue. BM=64 q-rows, BN=512 (full D), K=4096 kv, grid 256 = 1/CU.
// A (P) reg-staged: load -> exp2 -> bf16 -> swizzled ds_write; B (Vt chunk)
// via gload16 pre-swizzled (T2). 8 waves each own 64 d-cols; acc[4][4].
// Block-id remap keeps each XCD on one batch (Vt 4MB L2-resident).
// ---------------------------------------------------------------------------
__global__ __launch_bounds__(512, 2) void fused_smpv(
    const bf16* __restrict__ Sim, const bf16* __restrict__ Vt,
    bf16* __restrict__ Ob) {
  __shared__ __align__(16) bf16 Apv[2][64 * 64];    // P chunk (8KB each)
  __shared__ __align__(16) bf16 Bpv[2][512 * 64];   // Vt chunk (64KB each)
  __shared__ float rl_lds[64];

  const int id = blockIdx.x + (blockIdx.y << 6);    // 0..255
  const int bz = (id >> 1) & 3;                     // batch
  const int by = ((id >> 3) << 1) | (id & 1);       // q row-tile 0..63

  const int tid = threadIdx.x;
  const bf16* Simb = Sim + (long)bz * ((long)SEQ * SEQ) + (long)(by * 64) * SEQ;
  const bf16* Vb   = Vt  + (long)bz * ((long)SEQ * CH);
  bf16* Obb        = Ob  + (long)bz * ((long)SEQ * CH) + (long)(by * 64) * CH;

  const int srow = tid >> 3;        // 0..63: A row / stage row
  const int sp = tid & 7;           // 16B slot
  const int slog = (sp ^ (srow & 7)) << 3;   // pre-swizzled source col (elems)
  const int aswz = (sp ^ (srow & 7)) << 4;   // swizzled LDS byte slot

  const int w = tid >> 6, lane = tid & 63;
  const int l16 = lane & 15, quad = lane >> 4;
  const int pA0 = (quad ^ (l16 & 7)) << 3;
  const int pA1 = pA0 ^ 32;

  float lsum = 0.f;  // partial exp-sum for row srow, cols sp*8+.. (mod 64)

  auto stageB8 = [&](int buf, int kt) {
    const bf16* s = Vb + (long)srow * SEQ + kt * 64 + slog;
    char* d = (char*)(&Bpv[buf][0]) + tid * 16;
    #pragma unroll
    for (int r = 0; r < 8; ++r)
      gload16(s + (long)(r * 64) * SEQ, d + r * 8192);
  };
  auto writeA = [&](int buf, uint4 u) {
    const ushort* h = (const ushort*)&u;
    union { uint4 u4; ushort hh[8]; } pk;
    #pragma unroll
    for (int k2 = 0; k2 < 8; ++k2) {
      float f = __uint_as_float(((unsigned)h[k2]) << 16);
      float e = hw_exp2(f);          // P = 2^(s*log2e) = e^s
      lsum += e;
      __hip_bfloat16 pb = __float2bfloat16(e);
      pk.hh[k2] = *(const ushort*)&pb;
    }
    *(uint4*)((char*)(&Apv[buf][0]) + srow * 128 + aswz) = pk.u4;
  };

  // ---- prologue: chunk 0 ----
  {
    uint4 ua = *(const uint4*)(Simb + (long)srow * SEQ + sp * 8);
    stageB8(0, 0);
    writeA(0, ua);
  }
  __syncthreads();

  floatx4 acc[4][4];
  #pragma unroll
  for (int i = 0; i < 4; ++i)
    #pragma unroll
    for (int j = 0; j < 4; ++j) acc[i][j] = (floatx4)(0.0f);

  const int nk = SEQ >> 6;  // 64 chunks
  for (int t = 0; t < nk; ++t) {
    const int cur = t & 1, nxt = cur ^ 1;
    const bool more = (t + 1 < nk);
    uint4 un;
    if (more) {
      un = *(const uint4*)(Simb + (long)srow * SEQ + (t + 1) * 64 + sp * 8);
      stageB8(nxt, t + 1);
    }
    short8 a[2][4], b[2][4];
    #pragma unroll
    for (int kc = 0; kc < 2; ++kc) {
      const int poff = kc ? pA1 : pA0;
      #pragma unroll
      for (int i = 0; i < 4; ++i)
        a[kc][i] = *(const short8*)(&Apv[cur][0] + (i * 16 + l16) * 64 + poff);
      #pragma unroll
      for (int j = 0; j < 4; ++j)
        b[kc][j] = *(const short8*)(&Bpv[cur][0]
                                    + (w * 64 + j * 16 + l16) * 64 + poff);
    }
    __builtin_amdgcn_s_setprio(1);
    #pragma unroll
    for (int kc = 0; kc < 2; ++kc)
      #pragma unroll
      for (int i = 0; i < 4; ++i)
        #pragma unroll
        for (int j = 0; j < 4; ++j)
          acc[i][j] = __builtin_amdgcn_mfma_f32_16x16x32_bf16(
              a[kc][i], b[kc][j], acc[i][j], 0, 0, 0);
    __builtin_amdgcn_s_setprio(0);
    if (more) writeA(nxt, un);
    __syncthreads();  // drains B gloads + A ds_write, swap-safe
  }

  // ---- row exp-sum reduce (8 lanes per row are contiguous in-wave) ----
  #pragma unroll
  for (int o = 1; o < 8; o <<= 1) lsum += __shfl_xor(lsum, o);
  if (sp == 0) rl_lds[srow] = 1.0f / lsum;
  __syncthreads();

  // ---- epilogue: O * (1/l), bf16, row-major [s][d] ----
  #pragma unroll
  for (int i = 0; i < 4; ++i) {
    #pragma unroll
    for (int j = 0; j < 4; ++j) {
      floatx4 v = acc[i][j];
      const int col = w * 64 + j * 16 + l16;
      #pragma unroll
      for (int r = 0; r < 4; ++r) {
        const int row = i * 16 + quad * 4 + r;
        Obb[(long)row * CH + col] = __float2bfloat16(v[r] * rl_lds[row]);
      }
    }
  }
}

// ---------------------------------------------------------------------------
// gemm_bn128: 256x128 tile, BK=64, 8 waves in 4Mx2N grid, per-wave 64x64.
// 2 phases per K-tile; TRIPLE-buffered LDS + counted vmcnt(6) (t+2 staging).
// MODE 0: bf16 = acc + bias[col], C[row*ldc+col]
// MODE 1: bf16 = acc + bias[col], transposed C[col*ldc+row]
// MODE 4: f32  = acc + bias[col], transposed C[col*ldc+row]
// ---------------------------------------------------------------------------
template <int MODE>
__global__ __launch_bounds__(512, 2) void gemm_bn128(
    const bf16* __restrict__ A, long sAz,
    const bf16* __restrict__ B, long sBz,
    void* __restrict__ Cv, long sCz,
    const float* __restrict__ bias, float scale,
    int K, int ldc) {
  __shared__ __align__(16) bf16 As[3][256 * 64];
  __shared__ __align__(16) bf16 Bs[3][128 * 64];

  int id = blockIdx.x + gridDim.x * (blockIdx.y + gridDim.y * blockIdx.z);
  int nwg = gridDim.x * gridDim.y * gridDim.z;
  int sid = ((nwg & 7) == 0) ? ((id & 7) * (nwg >> 3) + (id >> 3)) : id;
  const int bx = sid % gridDim.x;
  const int by = (sid / gridDim.x) % gridDim.y;
  const int bz = sid / (gridDim.x * gridDim.y);

  const int tid = threadIdx.x;
  const long lK = K;
  const bf16* Ab = A + (long)bz * sAz + (long)by * 256 * lK;
  const bf16* Bb = B + (long)bz * sBz + (long)bx * 128 * lK;

  const int w = tid >> 6, lane = tid & 63;
  const int wr = w >> 1, wc = w & 1;          // 4 x 2 wave grid
  const int l16 = lane & 15, quad = lane >> 4;

  const int srow = tid >> 3;
  const int sp = tid & 7;
  const int slog = (sp ^ (srow & 7)) << 3;

  const int pA0 = (quad ^ (l16 & 7)) << 3;
  const int pA1 = pA0 ^ 32;

  auto stageA = [&](int buf, int kt) {
    const bf16* s = Ab + (long)kt * 64 + (long)srow * lK + slog;
    char* d = (char*)(&As[buf][0]) + tid * 16;
    #pragma unroll
    for (int r = 0; r < 4; ++r)
      gload16(s + (long)(r * 64) * lK, d + r * 8192);
  };
  auto stageB = [&](int buf, int kt) {
    const bf16* s = Bb + (long)kt * 64 + (long)srow * lK + slog;
    char* d = (char*)(&Bs[buf][0]) + tid * 16;
    #pragma unroll
    for (int r = 0; r < 2; ++r)
      gload16(s + (long)(r * 64) * lK, d + r * 8192);
  };

  floatx4 acc[4][4];
  #pragma unroll
  for (int m = 0; m < 4; ++m)
    #pragma unroll
    for (int n = 0; n < 4; ++n) acc[m][n] = (floatx4)(0.0f);

  const int nk = K >> 6;
  stageA(0, 0); stageB(0, 0);
  stageA(1, 1); stageB(1, 1);
  asm volatile("s_waitcnt vmcnt(6)" ::: "memory");
  __builtin_amdgcn_s_barrier();

  int bcur = 0, bstage = 2;
  for (int t = 0; t < nk; ++t) {
    const bf16* __restrict__ Al = &As[bcur][0];
    const bf16* __restrict__ Bl = &Bs[bcur][0];
    const bool more = (t + 2 < nk);
    #pragma unroll
    for (int kc = 0; kc < 2; ++kc) {
      const int poff = kc ? pA1 : pA0;
      short8 a[4], b[4];
      #pragma unroll
      for (int i = 0; i < 4; ++i)
        a[i] = *(const short8*)(Al + (wr * 64 + i * 16 + l16) * 64 + poff);
      #pragma unroll
      for (int j = 0; j < 4; ++j)
        b[j] = *(const short8*)(Bl + (wc * 64 + j * 16 + l16) * 64 + poff);
      if (more) {
        if (kc == 0) stageA(bstage, t + 2);
        else         stageB(bstage, t + 2);
      }
      __builtin_amdgcn_s_barrier();
      __builtin_amdgcn_s_setprio(1);
      #pragma unroll
      for (int i = 0; i < 4; ++i)
        #pragma unroll
        for (int j = 0; j < 4; ++j)
          acc[i][j] = __builtin_amdgcn_mfma_f32_16x16x32_bf16(
              a[i], b[j], acc[i][j], 0, 0, 0);
      __builtin_amdgcn_s_setprio(0);
      if (kc == 1) {
        if (more)            asm volatile("s_waitcnt vmcnt(6)" ::: "memory");
        else if (t + 1 < nk) asm volatile("s_waitcnt vmcnt(0)" ::: "memory");
      }
      __builtin_amdgcn_s_barrier();
    }
    bcur = (bcur == 2) ? 0 : bcur + 1;
    bstage = (bstage == 2) ? 0 : bstage + 1;
  }

  const int rbase = by * 256 + wr * 64 + quad * 4;
  const int cbase = bx * 128 + wc * 64 + l16;
  #pragma unroll
  for (int m = 0; m < 4; ++m) {
    const int row = rbase + m * 16;
    #pragma unroll
    for (int n = 0; n < 4; ++n) {
      const int col = cbase + n * 16;
      floatx4 v = acc[m][n];
      if constexpr (MODE == 0) {
        bf16* C = (bf16*)Cv + (long)bz * sCz;
        const float bb = bias[col];
        #pragma unroll
        for (int r = 0; r < 4; ++r)
          C[(long)(row + r) * ldc + col] = __float2bfloat16(v[r] + bb);
      } else if constexpr (MODE == 1) {
        bf16* C = (bf16*)Cv + (long)bz * sCz;
        const float bb = bias[col];
        alignas(8) bf16 tmp[4];
        #pragma unroll
        for (int r = 0; r < 4; ++r) tmp[r] = __float2bfloat16(v[r] + bb);
        *(shortx4*)(C + (long)col * ldc + row) = *(const shortx4*)tmp;
      } else {  // MODE 4
        float* C = (float*)Cv + (long)bz * sCz;
        const float bb = bias[col];
        floatx4 o_;
        #pragma unroll
        for (int r = 0; r < 4; ++r) o_[r] = v[r] + bb;
        *(floatx4*)(C + (long)col * ldc + row) = o_;
      }
    }
  }
}

// ---------------------------------------------------------------------------
extern "C" void kernel_launch(void* const* d_in, const int* in_sizes, int n_in,
                              void* d_out, int out_size, void* d_ws,
                              size_t ws_size, hipStream_t stream) {
  const float* q  = (const float*)d_in[0];
  const float* Wq = (const float*)d_in[1];
  const float* bq = (const float*)d_in[2];
  const float* Wk = (const float*)d_in[3];
  const float* bk = (const float*)d_in[4];
  const float* Wv = (const float*)d_in[5];
  const float* bv = (const float*)d_in[6];
  const float* Wo = (const float*)d_in[7];
  const float* bo = (const float*)d_in[8];
  float* out = (float*)d_out;

  bf16* ws = (bf16*)d_ws;
  const long WSZ = (long)DM * CH;         // 262144 elems per weight matrix
  const long XSZ = (long)SEQ * CH;        // 2097152 elems per batch
  const long SSZ = (long)SEQ * SEQ;       // 16777216 elems per batch
  bf16* Wqb = ws;
  bf16* Wkb = Wqb + WSZ;
  bf16* Wvb = Wqb + 2 * WSZ;
  bf16* Wob = Wqb + 3 * WSZ;
  bf16* xT  = Wqb + 4 * WSZ;
  bf16* Qb  = xT + BATCH * XSZ;
  bf16* Kb  = Qb + BATCH * XSZ;
  bf16* Vt  = Kb + BATCH * XSZ;   // (b, d, s) layout
  bf16* Ob  = Vt + BATCH * XSZ;
  bf16* Sim = Ob + BATCH * XSZ;   // (b, s, t) bf16, pre-scaled by log2e

  cvt_weights<<<dim3(WSZ / 256, 4), 256, 0, stream>>>(Wq, Wk, Wv, Wo, ws);
  transpose_cvt<<<dim3(SEQ / 64, CH / 64, BATCH), 256, 0, stream>>>(q, xT);

  // Q = xT * Wq^T + bq  (4096x512x512), bf16 out, row-major [s][d]
  gemm_bn128<0><<<dim3(4, 16, BATCH), 512, 0, stream>>>(
      xT, XSZ, Wqb, 0, Qb, XSZ, bq, 1.f, CH, DM);
  gemm_bn128<0><<<dim3(4, 16, BATCH), 512, 0, stream>>>(
      xT, XSZ, Wkb, 0, Kb, XSZ, bk, 1.f, CH, DM);
  // V stored transposed: Vt[d][s]
  gemm_bn128<1><<<dim3(4, 16, BATCH), 512, 0, stream>>>(
      xT, XSZ, Wvb, 0, Vt, XSZ, bv, 1.f, CH, SEQ);
  // sim = Q*K^T * (scale*log2e) (4096x4096x512)
  const float qkscale = 0.04419417382415922f * 1.4426950408889634f;
  gemm_qk<<<dim3(16, 16, BATCH), 512, 0, stream>>>(
      Qb, XSZ, Kb, XSZ, Sim, SSZ, qkscale, CH, SEQ);
  // o = softmax(sim) * V, single-pass fused (exp2, l accumulated in-flight)
  fused_smpv<<<dim3(64, 4), 512, 0, stream>>>(Sim, Vt, Ob);
  // y = o * Wo^T + bo, stored transposed into d_out as (b, c, s) fp32
  gemm_bn128<4><<<dim3(4, 16, BATCH), 512, 0, stream>>>(
      Ob, XSZ, Wob, 0, out, XSZ, bo, 1.f, DM, SEQ);
}

// Round 10
// 338.368 us; speedup vs baseline: 1.1199x; 1.0419x over previous
//
#include <hip/hip_runtime.h>
#include <hip/hip_bf16.h>

typedef __hip_bfloat16 bf16;
typedef __attribute__((ext_vector_type(8))) short short8;
typedef __attribute__((ext_vector_type(4))) float floatx4;
typedef __attribute__((ext_vector_type(4))) short shortx4;

static constexpr int BATCH = 4;
static constexpr int CH    = 512;   // C
static constexpr int SEQ   = 4096;  // H*W
static constexpr int DM    = 512;   // model dim

__device__ __forceinline__ void gload16(const void* g, void* l) {
  __builtin_amdgcn_global_load_lds(
      (const __attribute__((address_space(1))) unsigned int*)g,
      (__attribute__((address_space(3))) unsigned int*)l,
      16, 0, 0);
}

// 2^x via the hardware transcendental (avoids glibc __exp2f macro collision)
__device__ __forceinline__ float hw_exp2(float x) {
  float r;
  asm("v_exp_f32 %0, %1" : "=v"(r) : "v"(x));
  return r;
}

// ---------------------------------------------------------------------------
// Weight fp32 -> bf16 conversion (4 matrices of 512x512)
// ---------------------------------------------------------------------------
__global__ __launch_bounds__(256) void cvt_weights(
    const float* __restrict__ w0, const float* __restrict__ w1,
    const float* __restrict__ w2, const float* __restrict__ w3,
    bf16* __restrict__ out) {
  const float* src = (blockIdx.y == 0) ? w0 : (blockIdx.y == 1) ? w1
                   : (blockIdx.y == 2) ? w2 : w3;
  int idx = blockIdx.x * 256 + threadIdx.x;
  out[(long)blockIdx.y * (DM * CH) + idx] = __float2bfloat16(src[idx]);
}

// ---------------------------------------------------------------------------
// x (b,c,s) fp32 -> xT (b,s,c) bf16, 64x64 LDS tiles
// ---------------------------------------------------------------------------
__global__ __launch_bounds__(256) void transpose_cvt(
    const float* __restrict__ x, bf16* __restrict__ xT) {
  __shared__ float tile[64][65];
  const int s0 = blockIdx.x * 64, c0 = blockIdx.y * 64;
  const float* xb = x + (long)blockIdx.z * CH * SEQ;
  bf16* xTb = xT + (long)blockIdx.z * SEQ * CH;
  const int t = threadIdx.x;
  const int sl = t & 63, cq = t >> 6;
  #pragma unroll
  for (int i = 0; i < 16; ++i) {
    int cl = cq * 16 + i;
    tile[cl][sl] = xb[(long)(c0 + cl) * SEQ + s0 + sl];
  }
  __syncthreads();
  const int cl2 = t & 63, sq = t >> 6;
  #pragma unroll
  for (int i = 0; i < 16; ++i) {
    int sl2 = sq * 16 + i;
    xTb[(long)(s0 + sl2) * CH + c0 + cl2] = __float2bfloat16(tile[cl2][sl2]);
  }
}

// ---------------------------------------------------------------------------
// proj128: 128x128 tile BT-GEMM for the K=512 projections. 256 threads,
// 4 waves (2x2, per-wave 64x64), BK=64, double-buffered, 64 KB LDS ->
// 2 blocks/CU (cross-block overlap hides the per-tile drain; m114 mechanism).
// KIND 0: QKV fused. grid.z = mat*4+batch (12). mat 0/1 -> bf16 row-major
//   [s][d] + bias; mat 2 -> bf16 transposed [d][s] + bias.
// KIND 1: out-proj. grid.z = batch (4). fp32 transposed [c][s] + bias.
// T1 XCD swizzle, T2 LDS XOR swizzle, T5 setprio.
// ---------------------------------------------------------------------------
template <int KIND>
__global__ __launch_bounds__(256, 2) void proj128(
    const bf16* __restrict__ A0, const bf16* __restrict__ Wbase,
    const float* __restrict__ b0, const float* __restrict__ b1,
    const float* __restrict__ b2, void* __restrict__ Cbase) {
  __shared__ __align__(16) bf16 As[2][128 * 64];
  __shared__ __align__(16) bf16 Bs[2][128 * 64];

  int id = blockIdx.x + gridDim.x * (blockIdx.y + gridDim.y * blockIdx.z);
  int nwg = gridDim.x * gridDim.y * gridDim.z;
  int sid = ((nwg & 7) == 0) ? ((id & 7) * (nwg >> 3) + (id >> 3)) : id;
  const int bx = sid % gridDim.x;
  const int by = (sid / gridDim.x) % gridDim.y;
  const int z  = sid / (gridDim.x * gridDim.y);
  const int mat = (KIND == 0) ? (z >> 2) : 0;
  const int bz  = (KIND == 0) ? (z & 3) : z;

  const long XSZ = (long)SEQ * CH;
  const long lK = CH;
  const bf16* Ab = A0 + (long)bz * XSZ + (long)by * 128 * lK;
  const bf16* Bb = Wbase + (long)mat * ((long)DM * CH) + (long)bx * 128 * lK;
  const float* bias = (KIND == 1) ? b0 : (mat == 0 ? b0 : mat == 1 ? b1 : b2);

  const int tid = threadIdx.x;
  const int w = tid >> 6, lane = tid & 63;
  const int wr = w >> 1, wc = w & 1;          // 2 x 2 wave grid
  const int l16 = lane & 15, quad = lane >> 4;
  const int srow = tid >> 3;                  // 0..31
  const int sp = tid & 7;
  const int slog = (sp ^ (srow & 7)) << 3;    // pre-swizzled source column
  const int pA0 = (quad ^ (l16 & 7)) << 3;
  const int pA1 = pA0 ^ 32;

  auto stageA = [&](int buf, int kt) {
    const bf16* s = Ab + kt * 64 + (long)srow * lK + slog;
    char* d = (char*)(&As[buf][0]) + tid * 16;
    #pragma unroll
    for (int r = 0; r < 4; ++r)
      gload16(s + (long)(r * 32) * lK, d + r * 4096);
  };
  auto stageB = [&](int buf, int kt) {
    const bf16* s = Bb + kt * 64 + (long)srow * lK + slog;
    char* d = (char*)(&Bs[buf][0]) + tid * 16;
    #pragma unroll
    for (int r = 0; r < 4; ++r)
      gload16(s + (long)(r * 32) * lK, d + r * 4096);
  };

  floatx4 acc[4][4];
  #pragma unroll
  for (int m = 0; m < 4; ++m)
    #pragma unroll
    for (int n = 0; n < 4; ++n) acc[m][n] = (floatx4)(0.0f);

  const int nk = CH >> 6;  // 8
  stageA(0, 0); stageB(0, 0);
  __syncthreads();

  for (int t = 0; t < nk; ++t) {
    const int cur = t & 1, nxt = cur ^ 1;
    const bool more = (t + 1 < nk);
    #pragma unroll
    for (int kc = 0; kc < 2; ++kc) {
      const int poff = kc ? pA1 : pA0;
      short8 a[4], b[4];
      #pragma unroll
      for (int i = 0; i < 4; ++i)
        a[i] = *(const short8*)(&As[cur][0] + (wr * 64 + i * 16 + l16) * 64 + poff);
      #pragma unroll
      for (int j = 0; j < 4; ++j)
        b[j] = *(const short8*)(&Bs[cur][0] + (wc * 64 + j * 16 + l16) * 64 + poff);
      if (more) {
        if (kc == 0) stageA(nxt, t + 1);
        else         stageB(nxt, t + 1);
      }
      __builtin_amdgcn_s_setprio(1);
      #pragma unroll
      for (int i = 0; i < 4; ++i)
        #pragma unroll
        for (int j = 0; j < 4; ++j)
          acc[i][j] = __builtin_amdgcn_mfma_f32_16x16x32_bf16(
              a[i], b[j], acc[i][j], 0, 0, 0);
      __builtin_amdgcn_s_setprio(0);
    }
    __syncthreads();  // drains vm+lgkm; buffer swap safe
  }

  const int rbase = by * 128 + wr * 64 + quad * 4;
  const int cbase = bx * 128 + wc * 64 + l16;
  #pragma unroll
  for (int m = 0; m < 4; ++m) {
    const int row = rbase + m * 16;
    #pragma unroll
    for (int n = 0; n < 4; ++n) {
      const int col = cbase + n * 16;
      floatx4 v = acc[m][n];
      const float bb = bias[col];
      if constexpr (KIND == 0) {
        if (mat < 2) {
          bf16* C = (bf16*)Cbase + (long)mat * (BATCH * XSZ) + (long)bz * XSZ;
          #pragma unroll
          for (int r = 0; r < 4; ++r)
            C[(long)(row + r) * DM + col] = __float2bfloat16(v[r] + bb);
        } else {
          bf16* C = (bf16*)Cbase + 2 * (BATCH * XSZ) + (long)bz * XSZ;
          alignas(8) bf16 tmp[4];
          #pragma unroll
          for (int r = 0; r < 4; ++r) tmp[r] = __float2bfloat16(v[r] + bb);
          *(shortx4*)(C + (long)col * SEQ + row) = *(const shortx4*)tmp;
        }
      } else {
        float* C = (float*)Cbase + (long)bz * XSZ;
        floatx4 o_;
        #pragma unroll
        for (int r = 0; r < 4; ++r) o_[r] = v[r] + bb;
        *(floatx4*)(C + (long)col * SEQ + row) = o_;
      }
    }
  }
}

// ---------------------------------------------------------------------------
// gemm_qk: 256x256 tile QK^T. Output PRE-SCALED by scale*log2(e) so the
// downstream softmax uses exp2 directly.
// ---------------------------------------------------------------------------
__global__ __launch_bounds__(512, 2) void gemm_qk(
    const bf16* __restrict__ A, long sAz,
    const bf16* __restrict__ B, long sBz,
    bf16* __restrict__ C, long sCz,
    float scale, int K, int ldc) {
  __shared__ __align__(16) bf16 As[2][256 * 64];
  __shared__ __align__(16) bf16 Bs[2][256 * 64];

  int id = blockIdx.x + gridDim.x * (blockIdx.y + gridDim.y * blockIdx.z);
  int nwg = gridDim.x * gridDim.y * gridDim.z;
  int sid = ((nwg & 7) == 0) ? ((id & 7) * (nwg >> 3) + (id >> 3)) : id;
  const int bx = sid % gridDim.x;
  const int by = (sid / gridDim.x) % gridDim.y;
  const int bz = sid / (gridDim.x * gridDim.y);

  const int tid = threadIdx.x;
  const long lK = K;
  const bf16* Ab = A + (long)bz * sAz + (long)by * 256 * lK;
  const bf16* Bb = B + (long)bz * sBz + (long)bx * 256 * lK;

  const int w = tid >> 6, lane = tid & 63;
  const int wr = w >> 2, wc = w & 3;          // 2 x 4 wave grid
  const int l16 = lane & 15, quad = lane >> 4;

  const int srow = tid >> 3;                  // 0..63
  const int sp = tid & 7;                     // physical 16B slot
  const int slog = (sp ^ (srow & 7)) << 3;    // pre-swizzled source column

  const int pA0 = (quad ^ (l16 & 7)) << 3;
  const int pA1 = pA0 ^ 32;

  auto stage_half = [&](const bf16* Gb, bf16* Lb, int kt, int h) {
    #pragma unroll
    for (int r = 0; r < 2; ++r) {
      const int row = h * 128 + r * 64 + srow;
      gload16(Gb + (long)kt * 64 + (long)row * lK + slog,
              (char*)Lb + row * 128 + sp * 16);
    }
  };

  floatx4 acc[8][4];
  #pragma unroll
  for (int m = 0; m < 8; ++m)
    #pragma unroll
    for (int n = 0; n < 4; ++n) acc[m][n] = (floatx4)(0.0f);

  const int nk = K >> 6;  // even
  stage_half(Ab, &As[0][0], 0, 0); stage_half(Bb, &Bs[0][0], 0, 0);
  stage_half(Ab, &As[0][0], 0, 1); stage_half(Bb, &Bs[0][0], 0, 1);
  if (nk > 1) { stage_half(Ab, &As[1][0], 1, 0); stage_half(Bb, &Bs[1][0], 1, 0); }
  asm volatile("s_waitcnt vmcnt(4)" ::: "memory");
  __builtin_amdgcn_s_barrier();

  for (int tt = 0; tt < nk; tt += 2) {
    #pragma unroll
    for (int u = 0; u < 2; ++u) {
      const bf16* __restrict__ Al = &As[u][0];
      const bf16* __restrict__ Bl = &Bs[u][0];
      short8 a[2][4], b[2][2][2];
      #pragma unroll
      for (int p = 0; p < 4; ++p) {
        const int rm = p >> 1, cn = p & 1;
        if (cn == 0) {
          #pragma unroll
          for (int kc = 0; kc < 2; ++kc)
            #pragma unroll
            for (int i = 0; i < 4; ++i)
              a[kc][i] = *(const short8*)(
                  Al + (rm * 128 + wr * 64 + i * 16 + l16) * 64
                     + (kc ? pA1 : pA0));
        }
        if (rm == 0) {
          #pragma unroll
          for (int kc = 0; kc < 2; ++kc)
            #pragma unroll
            for (int j = 0; j < 2; ++j)
              b[kc][cn][j] = *(const short8*)(
                  Bl + (cn * 128 + wc * 32 + j * 16 + l16) * 64
                     + (kc ? pA1 : pA0));
        }
        {
          const int g = u * 4 + p;
          const int stile = tt + 1 + ((g + 2) >> 2);
          if (stile < nk) {
            const int sh = (p < 2) ? 1 : 0;
            if (p & 1) stage_half(Bb, &Bs[stile & 1][0], stile, sh);
            else       stage_half(Ab, &As[stile & 1][0], stile, sh);
          }
        }
        __builtin_amdgcn_sched_barrier(0);
        __builtin_amdgcn_s_barrier();
        asm volatile("s_waitcnt lgkmcnt(0)" ::: "memory");
        __builtin_amdgcn_sched_barrier(0);
        __builtin_amdgcn_s_setprio(1);
        #pragma unroll
        for (int kc = 0; kc < 2; ++kc)
          #pragma unroll
          for (int i = 0; i < 4; ++i)
            #pragma unroll
            for (int j = 0; j < 2; ++j)
              acc[rm * 4 + i][cn * 2 + j] =
                  __builtin_amdgcn_mfma_f32_16x16x32_bf16(
                      a[kc][i], b[kc][cn][j], acc[rm * 4 + i][cn * 2 + j],
                      0, 0, 0);
        __builtin_amdgcn_s_setprio(0);
        if (p == 3) {
          if (u == 0) {
            if (tt + 2 < nk) asm volatile("s_waitcnt vmcnt(4)" ::: "memory");
            else             asm volatile("s_waitcnt vmcnt(0)" ::: "memory");
          } else {
            if (tt + 2 < nk) asm volatile("s_waitcnt vmcnt(4)" ::: "memory");
          }
        }
        __builtin_amdgcn_s_barrier();
      }
    }
  }

  bf16* Cb = C + (long)bz * sCz;
  #pragma unroll
  for (int rm = 0; rm < 2; ++rm)
    #pragma unroll
    for (int i = 0; i < 4; ++i) {
      const int row = by * 256 + rm * 128 + wr * 64 + i * 16 + quad * 4;
      #pragma unroll
      for (int cn = 0; cn < 2; ++cn)
        #pragma unroll
        for (int j = 0; j < 2; ++j) {
          const int col = bx * 256 + cn * 128 + wc * 32 + j * 16 + l16;
          floatx4 v = acc[rm * 4 + i][cn * 2 + j];
          #pragma unroll
          for (int r = 0; r < 4; ++r)
            Cb[(long)(row + r) * ldc + col] = __float2bfloat16(v[r] * scale);
        }
    }
}

// ---------------------------------------------------------------------------
// fused_smpv: SINGLE-PASS softmax + PV (exp2, no max-sub; l accumulated
// during P staging, applied in epilogue). BM=64 q-rows, BN=512 (full D),
// grid 256 = 1/CU. XCD-aware decode: each XCD (id&7) serves ONE batch
// (bz = (id&7)>>1) so that batch's Vt (4 MB) is L2-resident.
// ---------------------------------------------------------------------------
__global__ __launch_bounds__(512, 2) void fused_smpv(
    const bf16* __restrict__ Sim, const bf16* __restrict__ Vt,
    bf16* __restrict__ Ob) {
  __shared__ __align__(16) bf16 Apv[2][64 * 64];    // P chunk (8KB each)
  __shared__ __align__(16) bf16 Bpv[2][512 * 64];   // Vt chunk (64KB each)
  __shared__ float rl_lds[64];

  const int id = blockIdx.x + (blockIdx.y << 6);    // 0..255
  const int xcd = id & 7;
  const int bz = xcd >> 1;                          // 2 XCDs per batch
  const int by = ((id >> 3) << 1) | (id & 1);       // q row-tile 0..63

  const int tid = threadIdx.x;
  const bf16* Simb = Sim + (long)bz * ((long)SEQ * SEQ) + (long)(by * 64) * SEQ;
  const bf16* Vb   = Vt  + (long)bz * ((long)SEQ * CH);
  bf16* Obb        = Ob  + (long)bz * ((long)SEQ * CH) + (long)(by * 64) * CH;

  const int srow = tid >> 3;        // 0..63: A row / stage row
  const int sp = tid & 7;           // 16B slot
  const int slog = (sp ^ (srow & 7)) << 3;   // pre-swizzled source col (elems)
  const int aswz = (sp ^ (srow & 7)) << 4;   // swizzled LDS byte slot

  const int w = tid >> 6, lane = tid & 63;
  const int l16 = lane & 15, quad = lane >> 4;
  const int pA0 = (quad ^ (l16 & 7)) << 3;
  const int pA1 = pA0 ^ 32;

  float lsum = 0.f;  // partial exp-sum for row srow

  auto stageB8 = [&](int buf, int kt) {
    const bf16* s = Vb + (long)srow * SEQ + kt * 64 + slog;
    char* d = (char*)(&Bpv[buf][0]) + tid * 16;
    #pragma unroll
    for (int r = 0; r < 8; ++r)
      gload16(s + (long)(r * 64) * SEQ, d + r * 8192);
  };
  auto writeA = [&](int buf, uint4 u) {
    const ushort* h = (const ushort*)&u;
    union { uint4 u4; ushort hh[8]; } pk;
    #pragma unroll
    for (int k2 = 0; k2 < 8; ++k2) {
      float f = __uint_as_float(((unsigned)h[k2]) << 16);
      float e = hw_exp2(f);          // P = 2^(s*log2e) = e^s
      lsum += e;
      __hip_bfloat16 pb = __float2bfloat16(e);
      pk.hh[k2] = *(const ushort*)&pb;
    }
    *(uint4*)((char*)(&Apv[buf][0]) + srow * 128 + aswz) = pk.u4;
  };

  // ---- prologue: chunk 0 ----
  {
    uint4 ua = *(const uint4*)(Simb + (long)srow * SEQ + sp * 8);
    stageB8(0, 0);
    writeA(0, ua);
  }
  __syncthreads();

  floatx4 acc[4][4];
  #pragma unroll
  for (int i = 0; i < 4; ++i)
    #pragma unroll
    for (int j = 0; j < 4; ++j) acc[i][j] = (floatx4)(0.0f);

  const int nk = SEQ >> 6;  // 64 chunks
  for (int t = 0; t < nk; ++t) {
    const int cur = t & 1, nxt = cur ^ 1;
    const bool more = (t + 1 < nk);
    uint4 un;
    if (more) {
      un = *(const uint4*)(Simb + (long)srow * SEQ + (t + 1) * 64 + sp * 8);
      stageB8(nxt, t + 1);
    }
    short8 a[2][4], b[2][4];
    #pragma unroll
    for (int kc = 0; kc < 2; ++kc) {
      const int poff = kc ? pA1 : pA0;
      #pragma unroll
      for (int i = 0; i < 4; ++i)
        a[kc][i] = *(const short8*)(&Apv[cur][0] + (i * 16 + l16) * 64 + poff);
      #pragma unroll
      for (int j = 0; j < 4; ++j)
        b[kc][j] = *(const short8*)(&Bpv[cur][0]
                                    + (w * 64 + j * 16 + l16) * 64 + poff);
    }
    __builtin_amdgcn_s_setprio(1);
    #pragma unroll
    for (int kc = 0; kc < 2; ++kc)
      #pragma unroll
      for (int i = 0; i < 4; ++i)
        #pragma unroll
        for (int j = 0; j < 4; ++j)
          acc[i][j] = __builtin_amdgcn_mfma_f32_16x16x32_bf16(
              a[kc][i], b[kc][j], acc[i][j], 0, 0, 0);
    __builtin_amdgcn_s_setprio(0);
    if (more) writeA(nxt, un);
    __syncthreads();  // drains B gloads + A ds_write, swap-safe
  }

  // ---- row exp-sum reduce (8 lanes per row are contiguous in-wave) ----
  #pragma unroll
  for (int o = 1; o < 8; o <<= 1) lsum += __shfl_xor(lsum, o);
  if (sp == 0) rl_lds[srow] = 1.0f / lsum;
  __syncthreads();

  // ---- epilogue: O * (1/l), bf16, row-major [s][d] ----
  #pragma unroll
  for (int i = 0; i < 4; ++i) {
    #pragma unroll
    for (int j = 0; j < 4; ++j) {
      floatx4 v = acc[i][j];
      const int col = w * 64 + j * 16 + l16;
      #pragma unroll
      for (int r = 0; r < 4; ++r) {
        const int row = i * 16 + quad * 4 + r;
        Obb[(long)row * CH + col] = __float2bfloat16(v[r] * rl_lds[row]);
      }
    }
  }
}

// ---------------------------------------------------------------------------
extern "C" void kernel_launch(void* const* d_in, const int* in_sizes, int n_in,
                              void* d_out, int out_size, void* d_ws,
                              size_t ws_size, hipStream_t stream) {
  const float* q  = (const float*)d_in[0];
  const float* Wq = (const float*)d_in[1];
  const float* bq = (const float*)d_in[2];
  const float* Wk = (const float*)d_in[3];
  const float* bk = (const float*)d_in[4];
  const float* Wv = (const float*)d_in[5];
  const float* bv = (const float*)d_in[6];
  const float* Wo = (const float*)d_in[7];
  const float* bo = (const float*)d_in[8];
  float* out = (float*)d_out;

  bf16* ws = (bf16*)d_ws;
  const long WSZ = (long)DM * CH;         // 262144 elems per weight matrix
  const long XSZ = (long)SEQ * CH;        // 2097152 elems per batch
  const long SSZ = (long)SEQ * SEQ;       // 16777216 elems per batch
  bf16* Wqb = ws;                          // Wq,Wk,Wv,Wo contiguous
  bf16* Wob = Wqb + 3 * WSZ;
  bf16* xT  = Wqb + 4 * WSZ;
  bf16* Qb  = xT + BATCH * XSZ;            // Q,K,Vt contiguous (proj128 kind 0)
  bf16* Kb  = Qb + BATCH * XSZ;
  bf16* Vt  = Kb + BATCH * XSZ;   // (b, d, s) layout
  bf16* Ob  = Vt + BATCH * XSZ;
  bf16* Sim = Ob + BATCH * XSZ;   // (b, s, t) bf16, pre-scaled by log2e

  cvt_weights<<<dim3(WSZ / 256, 4), 256, 0, stream>>>(Wq, Wk, Wv, Wo, ws);
  transpose_cvt<<<dim3(SEQ / 64, CH / 64, BATCH), 256, 0, stream>>>(q, xT);

  // Q,K,V projections fused into one launch (z = mat*4 + batch)
  proj128<0><<<dim3(4, 32, 12), 256, 0, stream>>>(
      xT, Wqb, bq, bk, bv, Qb);
  // sim = Q*K^T * (scale*log2e) (4096x4096x512)
  const float qkscale = 0.04419417382415922f * 1.4426950408889634f;
  gemm_qk<<<dim3(16, 16, BATCH), 512, 0, stream>>>(
      Qb, XSZ, Kb, XSZ, Sim, SSZ, qkscale, CH, SEQ);
  // o = softmax(sim) * V, single-pass fused
  fused_smpv<<<dim3(64, 4), 512, 0, stream>>>(Sim, Vt, Ob);
  // y = o * Wo^T + bo, stored transposed into d_out as (b, c, s) fp32
  proj128<1><<<dim3(4, 32, 4), 256, 0, stream>>>(
      Ob, Wob, bo, nullptr, nullptr, out);
}